// Round 2
// baseline (589.498 us; speedup 1.0000x reference)
//
#include <hip/hip_runtime.h>

typedef __bf16 bf16_t;
typedef __bf16 bf16x4 __attribute__((ext_vector_type(4)));
typedef __bf16 bf16x8 __attribute__((ext_vector_type(8)));
typedef float f32x4 __attribute__((ext_vector_type(4)));

// XOR swizzle of the 16B-slot index within a 128B LDS row (8 slots):
__device__ __forceinline__ int swz(int row) { return (row ^ (row >> 3)) & 7; }

__device__ __forceinline__ f32x4 mfma16(bf16x8 a, bf16x8 b, f32x4 c) {
  return __builtin_amdgcn_mfma_f32_16x16x32_bf16(a, b, c, 0, 0, 0);
}

__device__ __forceinline__ void gl_lds16(const void* g, void* l) {
  __builtin_amdgcn_global_load_lds(
      (const __attribute__((address_space(1))) unsigned int*)g,
      (__attribute__((address_space(3))) unsigned int*)l, 16, 0, 0);
}

// ---------------------------------------------------------------------------
// f32 -> bf16 convert (weights): one thread = 4 elements
// ---------------------------------------------------------------------------
__global__ __launch_bounds__(256) void cvtw_kernel(const float* __restrict__ s,
                                                   bf16_t* __restrict__ d) {
  int i = blockIdx.x * 256 + threadIdx.x;
  float4 v = ((const float4*)s)[i];
  bf16x4 o;
  o[0] = (bf16_t)v.x; o[1] = (bf16_t)v.y; o[2] = (bf16_t)v.z; o[3] = (bf16_t)v.w;
  ((bf16x4*)d)[i] = o;
}

// ---------------------------------------------------------------------------
// Mask pack: int32 [16,1024,1024] -> bits [16,1024,32] u32
// ---------------------------------------------------------------------------
__global__ __launch_bounds__(256) void pack_mask_kernel(
    const int* __restrict__ mask, unsigned* __restrict__ bits) {
  int idx = blockIdx.x * 256 + threadIdx.x;  // word index, 524288 total
  const int4* src = (const int4*)(mask + (size_t)idx * 32);
  unsigned w = 0;
#pragma unroll
  for (int i = 0; i < 8; ++i) {
    int4 v = src[i];
    w |= (v.x != 0 ? 1u : 0u) << (i * 4 + 0);
    w |= (v.y != 0 ? 1u : 0u) << (i * 4 + 1);
    w |= (v.z != 0 ? 1u : 0u) << (i * 4 + 2);
    w |= (v.w != 0 ? 1u : 0u) << (i * 4 + 3);
  }
  bits[idx] = w;
}

// ---------------------------------------------------------------------------
// GEMM body: O[m][n] = sum_k A[m][k]*W[n][k] + bias[n]
// A: [16384,1024] (f32 or bf16), W: [1024,1024] bf16 row-major (= B^T layout)
// Tile 128x128, BK=64, 4 waves (2x2), 16x16x32 bf16 MFMA, swizzled LDS.
// ---------------------------------------------------------------------------
template <typename AT, typename OT>
__device__ __forceinline__ void gemm_body(const AT* __restrict__ A,
                                          const bf16_t* __restrict__ W,
                                          const float* __restrict__ bias,
                                          OT* __restrict__ O) {
  __shared__ __align__(16) bf16_t As[128 * 64];
  __shared__ __align__(16) bf16_t Bs[128 * 64];

  const int t = threadIdx.x;
  const int lane = t & 63;
  const int wid = t >> 6;
  const int g = lane >> 4;
  const int lr = lane & 15;
  const int wm = wid >> 1, wn = wid & 1;
  const int m0 = blockIdx.y * 128, n0 = blockIdx.x * 128;

  f32x4 acc[4][4] = {};

  for (int kb = 0; kb < 1024; kb += 64) {
    __syncthreads();
#pragma unroll
    for (int rr = 0; rr < 4; ++rr) {
      int s = rr * 256 + t;          // 16B-slot index 0..1023
      int row = s >> 3, c = s & 7;   // tile row, logical k-chunk
      if constexpr (sizeof(AT) == 4) {
        // f32 A: load 8 floats, convert, swizzled ds_write_b128
        const float4* ap =
            (const float4*)((const float*)A + (size_t)(m0 + row) * 1024 + kb + c * 8);
        float4 u0 = ap[0], u1 = ap[1];
        float fv[8] = {u0.x, u0.y, u0.z, u0.w, u1.x, u1.y, u1.z, u1.w};
        bf16x8 av;
#pragma unroll
        for (int e = 0; e < 8; ++e) av[e] = (bf16_t)fv[e];
        *(bf16x8*)&As[((row << 3) + (c ^ swz(row))) * 8] = av;
      } else {
        // bf16 A: direct global->LDS with pre-swizzled source
        gl_lds16((const bf16_t*)A + (size_t)(m0 + row) * 1024 + kb + (c ^ swz(row)) * 8,
                 &As[(rr * 256 + wid * 64) * 8]);
      }
      gl_lds16(W + (size_t)(n0 + row) * 1024 + kb + (c ^ swz(row)) * 8,
               &Bs[(rr * 256 + wid * 64) * 8]);
    }
    __syncthreads();
#pragma unroll
    for (int kk = 0; kk < 2; ++kk) {  // two K=32 chunks
      bf16x8 a[4], b[4];
#pragma unroll
      for (int i = 0; i < 4; ++i) {
        int row = wm * 64 + i * 16 + lr;
        int slot = (kk * 4 + g) ^ swz(row);
        a[i] = *(const bf16x8*)&As[row * 64 + slot * 8];
      }
#pragma unroll
      for (int j = 0; j < 4; ++j) {
        int row = wn * 64 + j * 16 + lr;
        int slot = (kk * 4 + g) ^ swz(row);
        b[j] = *(const bf16x8*)&Bs[row * 64 + slot * 8];
      }
#pragma unroll
      for (int i = 0; i < 4; ++i)
#pragma unroll
        for (int j = 0; j < 4; ++j)
          acc[i][j] = mfma16(a[i], b[j], acc[i][j]);
    }
  }

  // epilogue: C/D layout col=lr, row=4*g+r
  float bval[4];
#pragma unroll
  for (int j = 0; j < 4; ++j) bval[j] = bias[n0 + wn * 64 + j * 16 + lr];
#pragma unroll
  for (int i = 0; i < 4; ++i)
#pragma unroll
    for (int r = 0; r < 4; ++r) {
      int row = m0 + wm * 64 + i * 16 + g * 4 + r;
#pragma unroll
      for (int j = 0; j < 4; ++j) {
        int n = n0 + wn * 64 + j * 16 + lr;
        O[(size_t)row * 1024 + n] = (OT)(acc[i][j][r] + bval[j]);
      }
    }
}

__global__ __launch_bounds__(256) void gemm_qkv_kernel(
    const float* key, const float* query, const float* value,
    const bf16_t* Wkb, const bf16_t* Wqb, const bf16_t* Wvb, const float* bk,
    const float* bq, const float* bv, bf16_t* ko, bf16_t* qo, bf16_t* vo) {
  const float *A, *bi;
  const bf16_t* W;
  bf16_t* O;
  if (blockIdx.z == 0) {
    A = key; W = Wkb; bi = bk; O = ko;
  } else if (blockIdx.z == 1) {
    A = query; W = Wqb; bi = bq; O = qo;
  } else {
    A = value; W = Wvb; bi = bv; O = vo;
  }
  gemm_body<float, bf16_t>(A, W, bi, O);
}

__global__ __launch_bounds__(256) void gemm_out_kernel(
    const bf16_t* __restrict__ A, const bf16_t* __restrict__ W,
    const float* __restrict__ b, float* __restrict__ O) {
  gemm_body<bf16_t, float>(A, W, b, O);
}

// ---------------------------------------------------------------------------
// Flash attention: WG = (q-block of 64, head, batch); 4 waves x 16 q-rows.
// ---------------------------------------------------------------------------
__global__ __launch_bounds__(256) void attn_kernel(
    const bf16_t* __restrict__ q_ws, const bf16_t* __restrict__ k_ws,
    const bf16_t* __restrict__ v_ws, const unsigned* __restrict__ mbits,
    bf16_t* __restrict__ y_ws) {
  __shared__ __align__(16) bf16_t Ks[64 * 64];       // [key][hd], swizzled
  __shared__ __align__(16) bf16_t Vt[64 * 64];       // [d][key], swizzled
  __shared__ __align__(16) unsigned Mb[64 * 32];     // mask bits [qrow][word]
  __shared__ __align__(16) bf16_t Ps[4][16 * 64];    // per-wave P, swizzled

  const int qb = blockIdx.x, h = blockIdx.y, b = blockIdx.z;
  const int t = threadIdx.x, lane = t & 63, wid = t >> 6;
  const int g = lane >> 4, lr = lane & 15;

  {  // mask bits for this q-block: 64 rows x 32 words
    const unsigned* src = mbits + ((size_t)(b * 1024 + qb * 64)) * 32;
    for (int i = t; i < 2048; i += 256) Mb[i] = src[i];
  }

  // Q fragments in registers (A-operand: row = lr, k = hd)
  bf16x8 qf[2];
  {
    const bf16_t* qp =
        q_ws + (size_t)(b * 1024 + qb * 64 + wid * 16 + lr) * 1024 + h * 64;
    qf[0] = *(const bf16x8*)(qp + g * 8);
    qf[1] = *(const bf16x8*)(qp + 32 + g * 8);
  }

  float m_r[4], l_r[4];
  f32x4 acc[4] = {};
#pragma unroll
  for (int r = 0; r < 4; ++r) { m_r[r] = -1e30f; l_r[r] = 0.f; }

  const bf16_t* Kb = k_ws + (size_t)(b * 1024) * 1024 + h * 64;
  const bf16_t* Vb = v_ws + (size_t)(b * 1024) * 1024 + h * 64;

  for (int kb = 0; kb < 16; ++kb) {
    __syncthreads();  // previous tile fully consumed
    // stage K tile [64 keys][64 hd] swizzled via pre-swizzled source
#pragma unroll
    for (int rr = 0; rr < 2; ++rr) {
      int s = rr * 256 + t;
      int row = s >> 3, st = s & 7;
      gl_lds16(Kb + (size_t)(kb * 64 + row) * 1024 + (st ^ swz(row)) * 8,
               &Ks[(rr * 256 + wid * 64) * 8]);
    }
    // stage V transposed: thread loads V[key][dblk*16..+16], writes Vt[d][key]
    {
      int keyr = t >> 2, dblk = t & 3;
      const bf16_t* vp = Vb + (size_t)(kb * 64 + keyr) * 1024 + dblk * 16;
      bf16x8 v0 = *(const bf16x8*)(vp);
      bf16x8 v1 = *(const bf16x8*)(vp + 8);
#pragma unroll
      for (int e = 0; e < 8; ++e) {
        int d0 = dblk * 16 + e;
        int d1 = d0 + 8;
        Vt[d0 * 64 + (((keyr >> 3) ^ swz(d0)) << 3) + (keyr & 7)] = v0[e];
        Vt[d1 * 64 + (((keyr >> 3) ^ swz(d1)) << 3) + (keyr & 7)] = v1[e];
      }
    }
    __syncthreads();

    // S = Q K^T for this wave's 16 q-rows x 64 keys
    float sv[4][4];
    float bmax[4] = {-3e38f, -3e38f, -3e38f, -3e38f};
#pragma unroll
    for (int ct = 0; ct < 4; ++ct) {
      f32x4 c = {};
#pragma unroll
      for (int kk = 0; kk < 2; ++kk) {
        int krow = ct * 16 + lr;  // B-operand: col = key = lr
        int slot = (kk * 4 + g) ^ swz(krow);
        bf16x8 kf = *(const bf16x8*)&Ks[krow * 64 + slot * 8];
        c = mfma16(qf[kk], kf, c);
      }
#pragma unroll
      for (int r = 0; r < 4; ++r) {
        int col = kb * 64 + ct * 16 + lr;
        unsigned mw = Mb[(wid * 16 + g * 4 + r) * 32 + (col >> 5)];
        float v = c[r] * 0.125f;
        v = ((mw >> (col & 31)) & 1u) ? v : -1e30f;
        sv[ct][r] = v;
        bmax[r] = fmaxf(bmax[r], v);
      }
    }
#pragma unroll
    for (int off = 1; off < 16; off <<= 1)
#pragma unroll
      for (int r = 0; r < 4; ++r)
        bmax[r] = fmaxf(bmax[r], __shfl_xor(bmax[r], off));

    float fs[4], psum[4];
#pragma unroll
    for (int r = 0; r < 4; ++r) {
      float mn = fmaxf(m_r[r], bmax[r]);
      fs[r] = __expf(m_r[r] - mn);
      m_r[r] = mn;
      psum[r] = 0.f;
    }
#pragma unroll
    for (int ct = 0; ct < 4; ++ct)
#pragma unroll
      for (int r = 0; r < 4; ++r) {
        float pv = __expf(sv[ct][r] - m_r[r]);  // masked -> exp(-huge) = 0
        psum[r] += pv;
        int prow = g * 4 + r;      // C/D row within wave tile
        int pcol = ct * 16 + lr;   // key col
        Ps[wid][prow * 64 + (((pcol >> 3) ^ swz(prow)) << 3) + (pcol & 7)] =
            (bf16_t)pv;
      }
#pragma unroll
    for (int off = 1; off < 16; off <<= 1)
#pragma unroll
      for (int r = 0; r < 4; ++r) psum[r] += __shfl_xor(psum[r], off);
#pragma unroll
    for (int r = 0; r < 4; ++r) l_r[r] = l_r[r] * fs[r] + psum[r];
#pragma unroll
    for (int dt = 0; dt < 4; ++dt)
#pragma unroll
      for (int r = 0; r < 4; ++r) acc[dt][r] *= fs[r];

    // PV: A = P[16 q][64 key] (wave-private LDS), B = V[key][d] via Vt rows
#pragma unroll
    for (int dt = 0; dt < 4; ++dt) {
#pragma unroll
      for (int kk2 = 0; kk2 < 2; ++kk2) {
        int aslot = (kk2 * 4 + g) ^ swz(lr);
        bf16x8 pa = *(const bf16x8*)&Ps[wid][lr * 64 + aslot * 8];
        int vrow = dt * 16 + lr;
        int vslot = (kk2 * 4 + g) ^ swz(vrow);
        bf16x8 vb = *(const bf16x8*)&Vt[vrow * 64 + vslot * 8];
        acc[dt] = mfma16(pa, vb, acc[dt]);
      }
    }
  }

  // epilogue: y[b][q][h*64 + d] = acc / l
#pragma unroll
  for (int r = 0; r < 4; ++r) {
    int qrow = qb * 64 + wid * 16 + g * 4 + r;
    float inv = 1.0f / fmaxf(l_r[r], 1e-30f);
#pragma unroll
    for (int dt = 0; dt < 4; ++dt) {
      y_ws[(size_t)(b * 1024 + qrow) * 1024 + h * 64 + dt * 16 + lr] =
          (bf16_t)(acc[dt][r] * inv);
    }
  }
}

// ---------------------------------------------------------------------------
extern "C" void kernel_launch(void* const* d_in, const int* in_sizes, int n_in,
                              void* d_out, int out_size, void* d_ws,
                              size_t ws_size, hipStream_t stream) {
  (void)in_sizes; (void)n_in; (void)out_size; (void)ws_size;
  const float* key = (const float*)d_in[0];
  const float* value = (const float*)d_in[1];
  const float* query = (const float*)d_in[2];
  const int* mask = (const int*)d_in[3];
  const float* Wk = (const float*)d_in[4];
  const float* bk = (const float*)d_in[5];
  const float* Wq = (const float*)d_in[6];
  const float* bq = (const float*)d_in[7];
  const float* Wv = (const float*)d_in[8];
  const float* bv = (const float*)d_in[9];
  const float* Wp = (const float*)d_in[10];
  const float* bp = (const float*)d_in[11];
  float* out = (float*)d_out;

  char* ws = (char*)d_ws;
  const size_t MB = 1ull << 20;
  unsigned* mbits = (unsigned*)(ws);                 // 2 MiB
  bf16_t* Wkb = (bf16_t*)(ws + 2 * MB);              // 2 MiB each
  bf16_t* Wqb = (bf16_t*)(ws + 4 * MB);
  bf16_t* Wvb = (bf16_t*)(ws + 6 * MB);
  bf16_t* Wpb = (bf16_t*)(ws + 8 * MB);
  bf16_t* k_ws = (bf16_t*)(ws + 10 * MB);            // 32 MiB each
  bf16_t* q_ws = (bf16_t*)(ws + 42 * MB);
  bf16_t* v_ws = (bf16_t*)(ws + 74 * MB);
  bf16_t* y_ws = (bf16_t*)(ws + 106 * MB);           // end: 138 MiB

  cvtw_kernel<<<1024, 256, 0, stream>>>(Wk, Wkb);
  cvtw_kernel<<<1024, 256, 0, stream>>>(Wq, Wqb);
  cvtw_kernel<<<1024, 256, 0, stream>>>(Wv, Wvb);
  cvtw_kernel<<<1024, 256, 0, stream>>>(Wp, Wpb);
  pack_mask_kernel<<<2048, 256, 0, stream>>>(mask, mbits);
  gemm_qkv_kernel<<<dim3(8, 128, 3), 256, 0, stream>>>(
      key, query, value, Wkb, Wqb, Wvb, bk, bq, bv, k_ws, q_ws, v_ws);
  attn_kernel<<<dim3(16, 16, 16), 256, 0, stream>>>(q_ws, k_ws, v_ws, mbits,
                                                    y_ws);
  gemm_out_kernel<<<dim3(8, 128), 256, 0, stream>>>(y_ws, Wpb, bp, out);
}